// Round 7
// baseline (190.010 us; speedup 1.0000x reference)
//
#include <hip/hip_runtime.h>

#define NCH 2048
#define HW 196
#define NB 64
#define NOUT 48    // 32 downconv rows + 8 fc2 rows (cols 2048..4095) + 8 fc1 rows (cols 0..2047)
#define NCHUNK 8
#define CPC (NCH / NCHUNK)     // 256 channels per block
#define KS_PER_BLK (CPC / 32)  // 8 K-steps of 32 channels
#define KGTOT (NCH / 32)       // 64 global K-steps
#define NT 13                  // N-tiles of 16 (208 >= 196)
#define MT 3                   // M-tiles of 16 (48 outputs)
#define TILE_F (32 * HW)       // 6272 floats per K-step tile (25088 B, contiguous in x)
#define TILE_V4 (TILE_F / 4)   // 1568 float4
#define SLAB (NT * NOUT * 16)  // 9984 floats per (b,chunk) slab, layout [nt][ns16][o48]
#define SLAB8 (SLAB / 2)       // 4992 8-byte words
#define ROWSTRIDE (16 * NOUT)  // 768 floats per nt

typedef __attribute__((ext_vector_type(8))) short bf16x8;
typedef __attribute__((ext_vector_type(4))) float f32x4;
typedef __attribute__((ext_vector_type(4))) int i32x4;

__device__ __forceinline__ short f2bf(float f) {   // fp32->bf16 RNE (weights)
    unsigned int u = __float_as_uint(f);
    u = u + 0x7fffu + ((u >> 16) & 1u);
    return (short)(u >> 16);
}

__device__ __forceinline__ unsigned long long pack2(float a, float b) {
    union { float f[2]; unsigned long long u; } t;
    t.f[0] = a; t.f[1] = b; return t.u;
}

// k-slot permutation (bank-conflict fix): fragment element (kq, j) holds
// channel row R = kq*2 + (j&1) + (j>>1)*8. Puts the 4 kq-groups' LDS reads
// at bank offsets 0/8/16/24 (uniform 2-way = free) instead of all at 0
// (4-way). Applied identically to A (here) and B (conv read); R0's pass
// proves HW pairs A-slot (kq,j) with B-slot (kq,j), so the sum is invariant.
// ---------------------------------------------------------------------------
__global__ void build_afrag(const float* __restrict__ down_w,
                            const float* __restrict__ fc_w,
                            bf16x8* __restrict__ afrag,
                            unsigned int* __restrict__ cnt) {
    int t = blockIdx.x * 256 + threadIdx.x;        // 64*3*64 = 12288
    if (blockIdx.x == 0 && threadIdx.x < NB) cnt[threadIdx.x] = 0;
    if (t >= KGTOT * MT * 64) return;
    int lane = t & 63;
    int frag = t >> 6;
    int mt = frag % MT;
    int kg = frag / MT;
    int o = mt * 16 + (lane & 15);
    int kq = lane >> 4;
    bf16x8 v;
#pragma unroll
    for (int j = 0; j < 8; ++j) {
        int c = kg * 32 + kq * 2 + (j & 1) + ((j >> 1) << 3);   // permuted k-slot
        float w;
        if (o < 32)      w = down_w[o * NCH + c];
        else if (o < 40) w = fc_w[(o - 32) * (2 * NCH) + NCH + c];
        else             w = fc_w[(o - 40) * (2 * NCH) + c];
        v[j] = f2bf(w);
    }
    afrag[frag * 64 + lane] = v;
}

struct FinSM {
    float Ts[NOUT * HW];   // 37632 B
    float red[256];
    float gmp[32];
    float score[8];
    float xo[8];
    float sal[HW];
    float logit[8];
};

// ---------------------------------------------------------------------------
// R7: R6 with the part path reverted to the R2-PROVEN coherence mechanism:
// relaxed agent-scope __hip_atomic_store/load (compiler-lowered cache bits),
// widened 32b->64b (native 8B atomic). The R5/R6 failures (identical absmax
// = exactly one stale 256-ch chunk) indict the hand-rolled `sc1` asm path —
// never hand-roll cross-XCD cache-coherence flags. k-perm + parallel
// reductions KEPT: a pass validates them, a fail indicts them unambiguously.
// ---------------------------------------------------------------------------
__global__ __launch_bounds__(256) void conv_fin(const float* __restrict__ x,
                                                const bf16x8* __restrict__ afrag,
                                                const float* __restrict__ down_b,
                                                const float* __restrict__ fc_b,
                                                float* __restrict__ part,
                                                unsigned int* __restrict__ cnt,
                                                float* __restrict__ out) {
    __shared__ union {
        float ldsx[2][TILE_F];   // 50176 B
        FinSM fin;
    } sm;
    __shared__ int lastS;

    const int chunk = blockIdx.x;
    const int b = blockIdx.y;
    const int tid = threadIdx.x;
    const int wave = tid >> 6;
    const int lane = tid & 63;
    const int nsub = lane & 15;
    const int kq = lane >> 4;

    f32x4 acc[4][MT];
#pragma unroll
    for (int i = 0; i < 4; ++i)
#pragma unroll
        for (int m = 0; m < MT; ++m)
            acc[i][m] = (f32x4){0.f, 0.f, 0.f, 0.f};

    int pidx[4];
#pragma unroll
    for (int i = 0; i < 4; ++i) {
        int p = (wave + 4 * i) * 16 + nsub;
        pidx[i] = (p < HW) ? p : (HW - 1);   // clamp; junk cols skipped by finisher
    }

    const float* xtile0 = x + ((size_t)b * NCH + (size_t)chunk * CPC) * HW;

    auto stage = [&](int ks, int bb) {
        const float* g = xtile0 + (size_t)ks * TILE_F;
#pragma unroll
        for (int r = 0; r < 7; ++r) {              // ceil(1568/256)
            int q = r * 256 + tid;
            if (q < TILE_V4) {
                __builtin_amdgcn_global_load_lds(
                    (const __attribute__((address_space(1))) unsigned int*)(g + (size_t)q * 4),
                    (__attribute__((address_space(3))) unsigned int*)(&sm.ldsx[bb][(r * 256 + wave * 64) * 4]),
                    16, 0, 0);
            }
        }
    };

    stage(0, 0);

    for (int ks = 0; ks < KS_PER_BLK; ++ks) {
        __syncthreads();                  // barrier drains vmcnt -> tile ks visible
        if (ks + 1 < KS_PER_BLK) stage(ks + 1, (ks + 1) & 1);

        const int kg = chunk * KS_PER_BLK + ks;
        bf16x8 a0 = afrag[(kg * MT + 0) * 64 + lane];
        bf16x8 a1 = afrag[(kg * MT + 1) * 64 + lane];
        bf16x8 a2 = afrag[(kg * MT + 2) * 64 + lane];

        const float* base = &sm.ldsx[ks & 1][kq * 2 * HW];
#pragma unroll
        for (int i = 0; i < 4; ++i) {
            const float* bp = base + pidx[i];
            unsigned int u[8];
#pragma unroll
            for (int j = 0; j < 8; ++j)   // permuted rows: 2-way (free) banks
                u[j] = __float_as_uint(bp[((j & 1) + ((j >> 1) << 3)) * HW]) + 0x8000u;
            i32x4 bi;
            bi[0] = (int)__builtin_amdgcn_perm(u[1], u[0], 0x07060302u);
            bi[1] = (int)__builtin_amdgcn_perm(u[3], u[2], 0x07060302u);
            bi[2] = (int)__builtin_amdgcn_perm(u[5], u[4], 0x07060302u);
            bi[3] = (int)__builtin_amdgcn_perm(u[7], u[6], 0x07060302u);
            bf16x8 bv = __builtin_bit_cast(bf16x8, bi);
            acc[i][0] = __builtin_amdgcn_mfma_f32_16x16x32_bf16(a0, bv, acc[i][0], 0, 0, 0);
            acc[i][1] = __builtin_amdgcn_mfma_f32_16x16x32_bf16(a1, bv, acc[i][1], 0, 0, 0);
            acc[i][2] = __builtin_amdgcn_mfma_f32_16x16x32_bf16(a2, bv, acc[i][2], 0, 0, 0);
        }
    }

    // part store, layout [nt][ns16][o48]: R2-proven relaxed agent atomics,
    // widened to 64-bit (two 8B atomic stores per f32x4, 16B-aligned).
    float* pb = part + (size_t)(b * NCHUNK + chunk) * SLAB;
#pragma unroll
    for (int i = 0; i < 4; ++i) {
        int nt = wave + 4 * i;
        if (nt < NT) {
            float* d = pb + nt * ROWSTRIDE + nsub * NOUT + kq * 4;
#pragma unroll
            for (int m = 0; m < MT; ++m) {
                unsigned long long lo = pack2(acc[i][m][0], acc[i][m][1]);
                unsigned long long hi = pack2(acc[i][m][2], acc[i][m][3]);
                unsigned long long* q = (unsigned long long*)(d + m * 16);
                __hip_atomic_store(q,     lo, __ATOMIC_RELAXED, __HIP_MEMORY_SCOPE_AGENT);
                __hip_atomic_store(q + 1, hi, __ATOMIC_RELAXED, __HIP_MEMORY_SCOPE_AGENT);
            }
        }
    }

    __syncthreads();   // drains vmcnt(0): all slab stores at coherence point
    if (tid == 0) {
        unsigned int old = __hip_atomic_fetch_add(&cnt[b], 1u,
                                                  __ATOMIC_RELAXED, __HIP_MEMORY_SCOPE_AGENT);
        int last = (old == NCHUNK - 1);
        if (last)   // acquire orders the slab reads below
            (void)__hip_atomic_load(&cnt[b], __ATOMIC_ACQUIRE, __HIP_MEMORY_SCOPE_AGENT);
        lastS = last;
    }
    __syncthreads();
    if (!lastS) return;

    // --- finish: last block of batch b reduces the 8 slabs (8B atomics) ---
    {
        const unsigned long long* basep =
            (const unsigned long long*)(part + (size_t)b * NCHUNK * SLAB);
        for (int i8 = tid; i8 < SLAB8; i8 += 256) {
            float sx = 0.f, sy = 0.f;
#pragma unroll
            for (int ch = 0; ch < NCHUNK; ++ch) {
                unsigned long long u = __hip_atomic_load(
                    basep + (size_t)ch * SLAB8 + i8,
                    __ATOMIC_RELAXED, __HIP_MEMORY_SCOPE_AGENT);
                union { unsigned long long u; float f[2]; } t;
                t.u = u;
                sx += t.f[0]; sy += t.f[1];
            }
            int idx = i8 * 2;
            int ntv = idx / ROWSTRIDE;
            int rem = idx - ntv * ROWSTRIDE;
            int ns = rem / NOUT;
            int o0 = rem - ns * NOUT;           // even
            int p = ntv * 16 + ns;
            if (p < HW) {
                sm.fin.Ts[o0 * HW + p] = sx;
                sm.fin.Ts[(o0 + 1) * HW + p] = sy;
            }
        }
    }
    __syncthreads();

    {   // GMP: 8 threads per output row
        int o = tid >> 3, s8 = tid & 7;
        float m = -1e30f;
        for (int p = s8; p < HW; p += 8) m = fmaxf(m, sm.fin.Ts[o * HW + p]);
        sm.fin.red[tid] = m;
    }
    __syncthreads();
    if (tid < 32) {
        float m = sm.fin.red[tid * 8];
#pragma unroll
        for (int j = 1; j < 8; ++j) m = fmaxf(m, sm.fin.red[tid * 8 + j]);
        sm.fin.gmp[tid] = m + down_b[tid];
    }
    __syncthreads();

    if (tid < 8)
        sm.fin.score[tid] = 0.25f * (sm.fin.gmp[4 * tid] + sm.fin.gmp[4 * tid + 1] +
                                     sm.fin.gmp[4 * tid + 2] + sm.fin.gmp[4 * tid + 3]);
    __syncthreads();

    if (tid < 8) {
        float m = -1e30f;
        for (int k = 0; k < 8; ++k) m = fmaxf(m, sm.fin.score[k]);
        float se = 0.f;
        for (int k = 0; k < 8; ++k) se += expf(sm.fin.score[k] - m);
        float xo = sm.fin.score[tid] - m - logf(se);
        sm.fin.xo[tid] = xo;
        out[b * 8 + tid] = xo;
    }
    __syncthreads();

    if (tid < HW) {
        float s = 0.f;
#pragma unroll
        for (int k = 0; k < 8; ++k) {
            float bs = down_b[4 * k] + down_b[4 * k + 1] +
                       down_b[4 * k + 2] + down_b[4 * k + 3];
            float rs = sm.fin.Ts[(4 * k) * HW + tid] + sm.fin.Ts[(4 * k + 1) * HW + tid] +
                       sm.fin.Ts[(4 * k + 2) * HW + tid] + sm.fin.Ts[(4 * k + 3) * HW + tid] + bs;
            s += sm.fin.xo[k] * rs;
        }
        sm.fin.sal[tid] = s * (1.f / 32.f);
    }
    __syncthreads();

    {   // logits: 32 threads per class
        int c = tid >> 5, s32 = tid & 31;
        float t = 0.f;
        for (int p = s32; p < HW; p += 32)
            t += sm.fin.Ts[(40 + c) * HW + p] + sm.fin.sal[p] * sm.fin.Ts[(32 + c) * HW + p];
        sm.fin.red[tid] = t;
    }
    __syncthreads();
    if (tid < 8) {
        float t = 0.f;
#pragma unroll
        for (int j = 0; j < 32; ++j) t += sm.fin.red[tid * 32 + j];
        sm.fin.logit[tid] = t * (1.f / 196.f) + fc_b[tid];
    }
    __syncthreads();

    if (tid < 8) {
        float m = -1e30f;
        for (int k = 0; k < 8; ++k) m = fmaxf(m, sm.fin.logit[k]);
        float se = 0.f;
        for (int k = 0; k < 8; ++k) se += expf(sm.fin.logit[k] - m);
        out[NB * 8 + b * 8 + tid] = sm.fin.logit[tid] - m - logf(se);
    }
}

extern "C" void kernel_launch(void* const* d_in, const int* in_sizes, int n_in,
                              void* d_out, int out_size, void* d_ws, size_t ws_size,
                              hipStream_t stream) {
    const float* x      = (const float*)d_in[0];
    const float* down_w = (const float*)d_in[1];
    const float* down_b = (const float*)d_in[2];
    const float* fc_w   = (const float*)d_in[3];
    const float* fc_b   = (const float*)d_in[4];
    float* out = (float*)d_out;

    bf16x8* afrag = (bf16x8*)d_ws;                                        // 192 KiB
    float* part = (float*)((char*)d_ws + (size_t)KGTOT * MT * 64 * 16);   // 20.4 MiB
    unsigned int* cnt = (unsigned int*)((char*)part + (size_t)NB * NCHUNK * SLAB * 4);  // 256 B

    build_afrag<<<(KGTOT * MT * 64 + 255) / 256, 256, 0, stream>>>(down_w, fc_w, afrag, cnt);
    conv_fin<<<dim3(NCHUNK, NB), 256, 0, stream>>>(x, afrag, down_b, fc_b, part, cnt, out);
}